// Round 2
// baseline (177.951 us; speedup 1.0000x reference)
//
#include <hip/hip_runtime.h>
#include <math.h>

#define HH 256
#define WW 256
static constexpr int HW = HH * WW;
static constexpr float MIN_D = 0.1f;
static constexpr float MAX_D = 10.0f;
static constexpr float C1c = 1e-4f;   // 0.01^2
static constexpr float C2c = 9e-4f;   // 0.03^2

__device__ inline unsigned shdu(unsigned v, int o) {
    return (unsigned)__shfl_down((int)v, o, 64);
}

// ---------------------------------------------------------------------------
// Stage 1: weighted z-buffer scatter. 4 points/thread, float4 loads,
// HW fire-and-forget fp32 atomics (unsafeAtomicAdd -> global_atomic_add_f32).
// acc is interleaved (zw, wm) pairs so both adds hit one 64B line.
// ---------------------------------------------------------------------------
__global__ __launch_bounds__(256) void scatter_k(const float* __restrict__ pts,
                          const float* __restrict__ dens,
                          float* __restrict__ acc, int nthreads, int N) {
    int t = blockIdx.x * 256 + threadIdx.x;
    if (t >= nthreads) return;
    const float4* p4 = (const float4*)pts;
    float4 a = p4[3 * t];
    float4 b4 = p4[3 * t + 1];
    float4 c = p4[3 * t + 2];
    float xs[4] = {a.x, a.w, b4.z, c.y};
    float ys[4] = {a.y, b4.x, b4.w, c.z};
    float zs[4] = {a.z, b4.y, c.x, c.w};
    int base = 4 * t;
    int b = base / N;              // N % 4 == 0 -> all 4 points share a batch
    float* accb = acc + (size_t)b * (2 * HW);
#pragma unroll
    for (int k = 0; k < 4; ++k) {
        float z = zs[k];
        if (!(z > MIN_D)) continue;          // strict z > MIN_DEPTH
        float u = (xs[k] / z + 0.5f) * (float)WW;   // IEEE div: exact binning match
        float v = (ys[k] / z + 0.5f) * (float)HH;
        if (!(u >= 0.f && u < (float)WW && v >= 0.f && v < (float)HH)) continue;
        int ui = (int)floorf(u);             // in [0,255] given the guard
        int vi = (int)floorf(v);
        float dd = dens[base + k];           // load only for valid points
        float w = __builtin_amdgcn_rcpf(1.f + __expf(-dd));   // fast sigmoid
        int idx = (vi << 8) | ui;
        unsafeAtomicAdd(&accb[2 * idx],     z * w);
        unsafeAtomicAdd(&accb[2 * idx + 1], w);
    }
}

// ---------------------------------------------------------------------------
// Stage 2: depth = zw/wm (where wm>0) -> raw; per-batch min/max of valid
// pred & gt via uint-bit atomics.
// mm layout: [0..3]=minP, [4..7]=minG, [8..11]=maxP, [12..15]=maxG
// ---------------------------------------------------------------------------
__global__ __launch_bounds__(256) void finalize_k(const float2* __restrict__ acc,
                           const float* __restrict__ gt, float* __restrict__ raw,
                           unsigned* __restrict__ mm) {
    int i = blockIdx.x * 256 + threadIdx.x;
    int b = blockIdx.x >> 8;
    float2 p = acc[i];
    float d = p.y > 0.f ? p.x / p.y : 0.f;
    raw[i] = d;
    float g = gt[i];
    unsigned dmin = d > 0.f ? __float_as_uint(d) : 0xFFFFFFFFu;
    unsigned dmax = d > 0.f ? __float_as_uint(d) : 0u;
    unsigned gmin = g > 0.f ? __float_as_uint(g) : 0xFFFFFFFFu;
    unsigned gmax = g > 0.f ? __float_as_uint(g) : 0u;
    for (int o = 32; o; o >>= 1) {
        dmin = min(dmin, shdu(dmin, o));
        gmin = min(gmin, shdu(gmin, o));
        dmax = max(dmax, shdu(dmax, o));
        gmax = max(gmax, shdu(gmax, o));
    }
    __shared__ unsigned sm[4][4];
    int wid = threadIdx.x >> 6, lane = threadIdx.x & 63;
    if (lane == 0) { sm[0][wid] = dmin; sm[1][wid] = gmin; sm[2][wid] = dmax; sm[3][wid] = gmax; }
    __syncthreads();
    if (threadIdx.x == 0) {
        unsigned m0 = min(min(sm[0][0], sm[0][1]), min(sm[0][2], sm[0][3]));
        unsigned m1 = min(min(sm[1][0], sm[1][1]), min(sm[1][2], sm[1][3]));
        unsigned m2 = max(max(sm[2][0], sm[2][1]), max(sm[2][2], sm[2][3]));
        unsigned m3 = max(max(sm[3][0], sm[3][1]), max(sm[3][2], sm[3][3]));
        atomicMin(&mm[b], m0);
        atomicMin(&mm[4 + b], m1);
        atomicMax(&mm[8 + b], m2);
        atomicMax(&mm[12 + b], m3);
    }
}

// ---------------------------------------------------------------------------
// Stage 3: fused normalize + separable 11x11 box SSIM + masked L1 + final
// combine (last block via atomic ticket).
// accum[0]=ssim_sum, accum[1]=mask_sum, accum[2]=l1_sum
// ---------------------------------------------------------------------------
__global__ __launch_bounds__(256) void ssim_k(const float* __restrict__ raw,
                       const float* __restrict__ gt, const unsigned* __restrict__ mm,
                       float* __restrict__ accum, unsigned* __restrict__ ticket,
                       float* __restrict__ out, int nblocks) {
    __shared__ float sp[26][27], st[26][27];
    __shared__ float vs[5][16][27];
    __shared__ float sb[3][4];
    int z = blockIdx.z;
    const float* P = raw + (size_t)z * HW;
    const float* T = gt + (size_t)z * HW;

    bool hasP = mm[8 + z] != 0u;
    float pmin = __uint_as_float(mm[z]);
    float pmax = __uint_as_float(mm[8 + z]);
    float pmin_m = hasP ? fmaxf(pmin, MIN_D) : 0.f;
    float pscale = 1.f / ((hasP ? fminf(pmax, MAX_D) : MAX_D) - pmin_m + 1e-8f);
    bool hasG = mm[12 + z] != 0u;
    float gmin = __uint_as_float(mm[4 + z]);
    float gmax = __uint_as_float(mm[12 + z]);
    float gmin_m = hasG ? fmaxf(gmin, MIN_D) : 0.f;
    float gscale = 1.f / ((hasG ? fminf(gmax, MAX_D) : MAX_D) - gmin_m + 1e-8f);

    int tx = threadIdx.x, ty = threadIdx.y;
    int tid = ty * 16 + tx;
    int ox = blockIdx.x * 16 - 5, oy = blockIdx.y * 16 - 5;

    // phase 1: load + normalize 26x26 halo tiles (zero-padded outside image)
    for (int i = tid; i < 26 * 26; i += 256) {
        int r = i / 26, cc = i % 26;
        int gx = ox + cc, gy = oy + r;
        float pv = 0.f, tv = 0.f;
        if (gx >= 0 && gx < WW && gy >= 0 && gy < HH) {
            float d = P[gy * WW + gx];
            pv = (d - pmin_m) * pscale * (d > 0.f ? 1.f : 0.f);
            float g = T[gy * WW + gx];
            tv = (g - gmin_m) * gscale * (g > 0.f ? 1.f : 0.f);
        }
        sp[r][cc] = pv; st[r][cc] = tv;
    }
    __syncthreads();

    // phase 2: vertical 11-sums of the 5 pooled quantities
    for (int i = tid; i < 16 * 26; i += 256) {
        int r = i / 26, cc = i % 26;   // r = output row within tile
        float s1 = 0, s2 = 0, s11 = 0, s22 = 0, s12 = 0;
#pragma unroll
        for (int k = 0; k < 11; ++k) {
            float p = sp[r + k][cc], q = st[r + k][cc];
            s1 += p; s2 += q;
            s11 = fmaf(p, p, s11); s22 = fmaf(q, q, s22); s12 = fmaf(p, q, s12);
        }
        vs[0][r][cc] = s1; vs[1][r][cc] = s2; vs[2][r][cc] = s11;
        vs[3][r][cc] = s22; vs[4][r][cc] = s12;
    }
    __syncthreads();

    // phase 3: horizontal 11-sums + SSIM formula
    float s1 = 0, s2 = 0, s11 = 0, s22 = 0, s12 = 0;
#pragma unroll
    for (int k = 0; k < 11; ++k) {
        s1  += vs[0][ty][tx + k];
        s2  += vs[1][ty][tx + k];
        s11 += vs[2][ty][tx + k];
        s22 += vs[3][ty][tx + k];
        s12 += vs[4][ty][tx + k];
    }
    const float inv121 = 1.f / 121.f;
    float mu1 = s1 * inv121, mu2 = s2 * inv121;
    float mu1sq = mu1 * mu1, mu2sq = mu2 * mu2, mu12 = mu1 * mu2;
    float sig1 = s11 * inv121 - mu1sq;
    float sig2 = s22 * inv121 - mu2sq;
    float sig12 = s12 * inv121 - mu12;
    float smap = (2.f * mu12 + C1c) * (2.f * sig12 + C2c) /
                 ((mu1sq + mu2sq + C1c) * (sig1 + sig2 + C2c));
    float pc = sp[ty + 5][tx + 5], tc = st[ty + 5][tx + 5];
    float m = (pc > 0.f && tc > 0.f) ? 1.f : 0.f;
    float sv = smap * m;
    float lv = m * fabsf(pc - tc);

    for (int o = 32; o; o >>= 1) {
        sv += __shfl_down(sv, o, 64);
        m  += __shfl_down(m, o, 64);
        lv += __shfl_down(lv, o, 64);
    }
    int wid = tid >> 6, lane = tid & 63;
    if (lane == 0) { sb[0][wid] = sv; sb[1][wid] = m; sb[2][wid] = lv; }
    __syncthreads();
    if (tid == 0) {
        unsafeAtomicAdd(&accum[0], sb[0][0] + sb[0][1] + sb[0][2] + sb[0][3]);
        unsafeAtomicAdd(&accum[1], sb[1][0] + sb[1][1] + sb[1][2] + sb[1][3]);
        unsafeAtomicAdd(&accum[2], sb[2][0] + sb[2][1] + sb[2][2] + sb[2][3]);
        __threadfence();                       // drain our adds (vmcnt)
        unsigned old = atomicAdd(ticket, 1u);
        if (old == (unsigned)(nblocks - 1)) {  // we're last: everyone's adds done
            __threadfence();
            float ss = __hip_atomic_load(&accum[0], __ATOMIC_RELAXED, __HIP_MEMORY_SCOPE_AGENT);
            float ms = __hip_atomic_load(&accum[1], __ATOMIC_RELAXED, __HIP_MEMORY_SCOPE_AGENT);
            float ls = __hip_atomic_load(&accum[2], __ATOMIC_RELAXED, __HIP_MEMORY_SCOPE_AGENT);
            float l1   = ls / (ms + 1e-8f);
            float ssim = 1.f - ss / (ms + 1e-8f);
            float total = fminf(0.8f * l1 + 0.2f * ssim, 1.0f);
            out[0] = (ms < 10.f) ? 0.f : total;
        }
    }
}

extern "C" void kernel_launch(void* const* d_in, const int* in_sizes, int n_in,
                              void* d_out, int out_size, void* d_ws, size_t ws_size,
                              hipStream_t stream) {
    const float* pts = (const float*)d_in[0];
    const float* dens = (const float*)d_in[1];
    const float* gt = (const float*)d_in[2];
    int B = in_sizes[2] / HW;      // 4
    int N = in_sizes[1] / B;       // 2,000,000

    float* ws = (float*)d_ws;
    float* acc  = ws;                               // [B*HW] float2 interleaved
    float* raw  = ws + (size_t)2 * B * HW;          // [B*HW]
    unsigned* mm = (unsigned*)(raw + (size_t)B * HW);  // 16 uints
    float* accum = (float*)(mm + 16);               // 3 floats
    unsigned* ticket = (unsigned*)(accum + 3);      // 1 uint

    // zero accumulators; min slots -> 0xFFFFFFFF; max slots + accum + ticket -> 0
    hipMemsetAsync(acc, 0, (size_t)2 * B * HW * sizeof(float), stream);
    hipMemsetAsync(mm, 0xFF, 8 * sizeof(unsigned), stream);
    hipMemsetAsync(mm + 8, 0, 8 * sizeof(unsigned) + 3 * sizeof(float) + sizeof(unsigned), stream);

    int nthreads = (B * N) / 4;
    scatter_k<<<(nthreads + 255) / 256, 256, 0, stream>>>(pts, dens, acc, nthreads, N);
    finalize_k<<<B * 256, 256, 0, stream>>>((const float2*)acc, gt, raw, mm);
    int nblocks = 16 * 16 * B;
    ssim_k<<<dim3(16, 16, B), dim3(16, 16), 0, stream>>>(raw, gt, mm, accum, ticket,
                                                         (float*)d_out, nblocks);
}

// Round 3
// 146.347 us; speedup vs baseline: 1.2160x; 1.2160x over previous
//
#include <hip/hip_runtime.h>
#include <math.h>

#define HH 256
#define WW 256
static constexpr int HW = HH * WW;
static constexpr float MIN_D = 0.1f;
static constexpr float MAX_D = 10.0f;
static constexpr float C1c = 1e-4f;   // 0.01^2
static constexpr float C2c = 9e-4f;   // 0.03^2
static constexpr float ZW_SCALE = 1048576.f;   // 2^20
static constexpr float W_SCALE  = 4194304.f;   // 2^22

__device__ inline unsigned shdu(unsigned v, int o) {
    return (unsigned)__shfl_down((int)v, o, 64);
}

// ---------------------------------------------------------------------------
// Stage 1: weighted z-buffer scatter. 8 points/thread, float4 loads, dens
// hoisted. ONE u64 fixed-point atomic per valid point:
//   hi32 = round(z*w * 2^20), lo32 = round(w * 2^22)
// (per-pixel sums bounded ~50 & ~15 << field capacities 2048 & 1024 -> no carry)
// Block 0 lanes also init mm/accum/ticket (read only after this kernel ends).
// ---------------------------------------------------------------------------
__global__ __launch_bounds__(256) void scatter_k(const float4* __restrict__ pts4,
                          const float4* __restrict__ dens4,
                          unsigned long long* __restrict__ acc,
                          unsigned* __restrict__ mm, float* __restrict__ accum,
                          unsigned* __restrict__ ticket, int nthreads, int N) {
    if (blockIdx.x == 0) {
        int tt = threadIdx.x;
        if (tt < 8) mm[tt] = 0xFFFFFFFFu;                 // minP, minG slots
        else if (tt < 16) mm[tt] = 0u;                    // maxP, maxG slots
        else if (tt < 19) accum[tt - 16] = 0.f;           // ssim/mask/l1 sums
        else if (tt == 19) *ticket = 0u;
    }
    int t = blockIdx.x * 256 + threadIdx.x;
    if (t >= nthreads) return;
    float4 P0 = pts4[6 * t], P1 = pts4[6 * t + 1], P2 = pts4[6 * t + 2];
    float4 P3 = pts4[6 * t + 3], P4 = pts4[6 * t + 4], P5 = pts4[6 * t + 5];
    float4 D0 = dens4[2 * t], D1 = dens4[2 * t + 1];
    float xs[8] = {P0.x, P0.w, P1.z, P2.y, P3.x, P3.w, P4.z, P5.y};
    float ys[8] = {P0.y, P1.x, P1.w, P2.z, P3.y, P4.x, P4.w, P5.z};
    float zs[8] = {P0.z, P1.y, P2.x, P2.w, P3.z, P4.y, P5.x, P5.w};
    float ds[8] = {D0.x, D0.y, D0.z, D0.w, D1.x, D1.y, D1.z, D1.w};
    int base = 8 * t;
    int b = base / N;              // N % 8 == 0 -> all 8 points share a batch
    unsigned long long* accb = acc + (size_t)b * HW;
#pragma unroll
    for (int k = 0; k < 8; ++k) {
        float z = zs[k];
        if (!(z > MIN_D)) continue;                 // strict z > MIN_DEPTH
        float u = (xs[k] / z + 0.5f) * (float)WW;   // IEEE div: exact binning
        float v = (ys[k] / z + 0.5f) * (float)HH;
        if (!(u >= 0.f && u < (float)WW && v >= 0.f && v < (float)HH)) continue;
        int ui = (int)u;                            // trunc == floor (u >= 0)
        int vi = (int)v;
        float w = __builtin_amdgcn_rcpf(1.f + __expf(-ds[k]));  // sigmoid
        unsigned hi = (unsigned)__float2int_rn(z * w * ZW_SCALE);
        unsigned lo = (unsigned)__float2int_rn(w * W_SCALE);
        unsigned long long pk = ((unsigned long long)hi << 32) | lo;
        atomicAdd(&accb[(vi << 8) | ui], pk);
    }
}

// ---------------------------------------------------------------------------
// Stage 2: depth = (hi/lo)*4 (where lo>0) -> raw; per-batch min/max of valid
// pred & gt via uint-bit atomics.
// mm layout: [0..3]=minP, [4..7]=minG, [8..11]=maxP, [12..15]=maxG
// ---------------------------------------------------------------------------
__global__ __launch_bounds__(256) void finalize_k(const unsigned long long* __restrict__ acc,
                           const float* __restrict__ gt, float* __restrict__ raw,
                           unsigned* __restrict__ mm) {
    int i = blockIdx.x * 256 + threadIdx.x;
    int b = blockIdx.x >> 8;
    unsigned long long v = acc[i];
    unsigned lo = (unsigned)v;
    unsigned hi = (unsigned)(v >> 32);
    float d = lo ? ((float)hi / (float)lo) * 4.0f : 0.f;   // (hi/2^20)/(lo/2^22)
    raw[i] = d;
    float g = gt[i];
    unsigned dmin = d > 0.f ? __float_as_uint(d) : 0xFFFFFFFFu;
    unsigned dmax = d > 0.f ? __float_as_uint(d) : 0u;
    unsigned gmin = g > 0.f ? __float_as_uint(g) : 0xFFFFFFFFu;
    unsigned gmax = g > 0.f ? __float_as_uint(g) : 0u;
    for (int o = 32; o; o >>= 1) {
        dmin = min(dmin, shdu(dmin, o));
        gmin = min(gmin, shdu(gmin, o));
        dmax = max(dmax, shdu(dmax, o));
        gmax = max(gmax, shdu(gmax, o));
    }
    __shared__ unsigned sm[4][4];
    int wid = threadIdx.x >> 6, lane = threadIdx.x & 63;
    if (lane == 0) { sm[0][wid] = dmin; sm[1][wid] = gmin; sm[2][wid] = dmax; sm[3][wid] = gmax; }
    __syncthreads();
    if (threadIdx.x == 0) {
        unsigned m0 = min(min(sm[0][0], sm[0][1]), min(sm[0][2], sm[0][3]));
        unsigned m1 = min(min(sm[1][0], sm[1][1]), min(sm[1][2], sm[1][3]));
        unsigned m2 = max(max(sm[2][0], sm[2][1]), max(sm[2][2], sm[2][3]));
        unsigned m3 = max(max(sm[3][0], sm[3][1]), max(sm[3][2], sm[3][3]));
        atomicMin(&mm[b], m0);
        atomicMin(&mm[4 + b], m1);
        atomicMax(&mm[8 + b], m2);
        atomicMax(&mm[12 + b], m3);
    }
}

// ---------------------------------------------------------------------------
// Stage 3: fused normalize + separable 11x11 box SSIM + masked L1 + final
// combine (last block via atomic ticket).
// accum[0]=ssim_sum, accum[1]=mask_sum, accum[2]=l1_sum
// ---------------------------------------------------------------------------
__global__ __launch_bounds__(256) void ssim_k(const float* __restrict__ raw,
                       const float* __restrict__ gt, const unsigned* __restrict__ mm,
                       float* __restrict__ accum, unsigned* __restrict__ ticket,
                       float* __restrict__ out, int nblocks) {
    __shared__ float sp[26][27], st[26][27];
    __shared__ float vs[5][16][27];
    __shared__ float sb[3][4];
    int z = blockIdx.z;
    const float* P = raw + (size_t)z * HW;
    const float* T = gt + (size_t)z * HW;

    bool hasP = mm[8 + z] != 0u;
    float pmin = __uint_as_float(mm[z]);
    float pmax = __uint_as_float(mm[8 + z]);
    float pmin_m = hasP ? fmaxf(pmin, MIN_D) : 0.f;
    float pscale = 1.f / ((hasP ? fminf(pmax, MAX_D) : MAX_D) - pmin_m + 1e-8f);
    bool hasG = mm[12 + z] != 0u;
    float gmin = __uint_as_float(mm[4 + z]);
    float gmax = __uint_as_float(mm[12 + z]);
    float gmin_m = hasG ? fmaxf(gmin, MIN_D) : 0.f;
    float gscale = 1.f / ((hasG ? fminf(gmax, MAX_D) : MAX_D) - gmin_m + 1e-8f);

    int tx = threadIdx.x, ty = threadIdx.y;
    int tid = ty * 16 + tx;
    int ox = blockIdx.x * 16 - 5, oy = blockIdx.y * 16 - 5;

    // phase 1: load + normalize 26x26 halo tiles (zero-padded outside image)
    for (int i = tid; i < 26 * 26; i += 256) {
        int r = i / 26, cc = i % 26;
        int gx = ox + cc, gy = oy + r;
        float pv = 0.f, tv = 0.f;
        if (gx >= 0 && gx < WW && gy >= 0 && gy < HH) {
            float d = P[gy * WW + gx];
            pv = (d - pmin_m) * pscale * (d > 0.f ? 1.f : 0.f);
            float g = T[gy * WW + gx];
            tv = (g - gmin_m) * gscale * (g > 0.f ? 1.f : 0.f);
        }
        sp[r][cc] = pv; st[r][cc] = tv;
    }
    __syncthreads();

    // phase 2: vertical 11-sums of the 5 pooled quantities
    for (int i = tid; i < 16 * 26; i += 256) {
        int r = i / 26, cc = i % 26;   // r = output row within tile
        float s1 = 0, s2 = 0, s11 = 0, s22 = 0, s12 = 0;
#pragma unroll
        for (int k = 0; k < 11; ++k) {
            float p = sp[r + k][cc], q = st[r + k][cc];
            s1 += p; s2 += q;
            s11 = fmaf(p, p, s11); s22 = fmaf(q, q, s22); s12 = fmaf(p, q, s12);
        }
        vs[0][r][cc] = s1; vs[1][r][cc] = s2; vs[2][r][cc] = s11;
        vs[3][r][cc] = s22; vs[4][r][cc] = s12;
    }
    __syncthreads();

    // phase 3: horizontal 11-sums + SSIM formula
    float s1 = 0, s2 = 0, s11 = 0, s22 = 0, s12 = 0;
#pragma unroll
    for (int k = 0; k < 11; ++k) {
        s1  += vs[0][ty][tx + k];
        s2  += vs[1][ty][tx + k];
        s11 += vs[2][ty][tx + k];
        s22 += vs[3][ty][tx + k];
        s12 += vs[4][ty][tx + k];
    }
    const float inv121 = 1.f / 121.f;
    float mu1 = s1 * inv121, mu2 = s2 * inv121;
    float mu1sq = mu1 * mu1, mu2sq = mu2 * mu2, mu12 = mu1 * mu2;
    float sig1 = s11 * inv121 - mu1sq;
    float sig2 = s22 * inv121 - mu2sq;
    float sig12 = s12 * inv121 - mu12;
    float smap = (2.f * mu12 + C1c) * (2.f * sig12 + C2c) /
                 ((mu1sq + mu2sq + C1c) * (sig1 + sig2 + C2c));
    float pc = sp[ty + 5][tx + 5], tc = st[ty + 5][tx + 5];
    float m = (pc > 0.f && tc > 0.f) ? 1.f : 0.f;
    float sv = smap * m;
    float lv = m * fabsf(pc - tc);

    for (int o = 32; o; o >>= 1) {
        sv += __shfl_down(sv, o, 64);
        m  += __shfl_down(m, o, 64);
        lv += __shfl_down(lv, o, 64);
    }
    int wid = tid >> 6, lane = tid & 63;
    if (lane == 0) { sb[0][wid] = sv; sb[1][wid] = m; sb[2][wid] = lv; }
    __syncthreads();
    if (tid == 0) {
        unsafeAtomicAdd(&accum[0], sb[0][0] + sb[0][1] + sb[0][2] + sb[0][3]);
        unsafeAtomicAdd(&accum[1], sb[1][0] + sb[1][1] + sb[1][2] + sb[1][3]);
        unsafeAtomicAdd(&accum[2], sb[2][0] + sb[2][1] + sb[2][2] + sb[2][3]);
        __threadfence();                       // drain our adds
        unsigned old = atomicAdd(ticket, 1u);
        if (old == (unsigned)(nblocks - 1)) {  // last block: all adds visible
            __threadfence();
            float ss = __hip_atomic_load(&accum[0], __ATOMIC_RELAXED, __HIP_MEMORY_SCOPE_AGENT);
            float ms = __hip_atomic_load(&accum[1], __ATOMIC_RELAXED, __HIP_MEMORY_SCOPE_AGENT);
            float ls = __hip_atomic_load(&accum[2], __ATOMIC_RELAXED, __HIP_MEMORY_SCOPE_AGENT);
            float l1   = ls / (ms + 1e-8f);
            float ssim = 1.f - ss / (ms + 1e-8f);
            float total = fminf(0.8f * l1 + 0.2f * ssim, 1.0f);
            out[0] = (ms < 10.f) ? 0.f : total;
        }
    }
}

extern "C" void kernel_launch(void* const* d_in, const int* in_sizes, int n_in,
                              void* d_out, int out_size, void* d_ws, size_t ws_size,
                              hipStream_t stream) {
    const float* pts = (const float*)d_in[0];
    const float* dens = (const float*)d_in[1];
    const float* gt = (const float*)d_in[2];
    int B = in_sizes[2] / HW;      // 4
    int N = in_sizes[1] / B;       // 2,000,000

    unsigned long long* acc = (unsigned long long*)d_ws;          // [B*HW] u64
    float* raw  = (float*)(acc + (size_t)B * HW);                 // [B*HW] f32
    unsigned* mm = (unsigned*)(raw + (size_t)B * HW);             // 16 u32
    float* accum = (float*)(mm + 16);                             // 3 f32
    unsigned* ticket = (unsigned*)(accum + 3);                    // 1 u32

    hipMemsetAsync(acc, 0, (size_t)B * HW * sizeof(unsigned long long), stream);

    int nthreads = (B * N) / 8;
    scatter_k<<<(nthreads + 255) / 256, 256, 0, stream>>>((const float4*)pts,
                                                          (const float4*)dens,
                                                          acc, mm, accum, ticket,
                                                          nthreads, N);
    finalize_k<<<B * 256, 256, 0, stream>>>(acc, gt, raw, mm);
    int nblocks = 16 * 16 * B;
    ssim_k<<<dim3(16, 16, B), dim3(16, 16), 0, stream>>>(raw, gt, mm, accum, ticket,
                                                         (float*)d_out, nblocks);
}

// Round 4
// 113.074 us; speedup vs baseline: 1.5738x; 1.2943x over previous
//
#include <hip/hip_runtime.h>
#include <math.h>

#define HH 256
#define WW 256
static constexpr int HW = HH * WW;
static constexpr float MIN_D = 0.1f;
static constexpr float MAX_D = 10.0f;
static constexpr float C1c = 1e-4f;   // 0.01^2
static constexpr float C2c = 9e-4f;   // 0.03^2
static constexpr float ZW_SCALE = 1048576.f;   // 2^20
static constexpr float W_SCALE  = 4194304.f;   // 2^22

__device__ inline unsigned shdu(unsigned v, int o) {
    return (unsigned)__shfl_down((int)v, o, 64);
}

// ---------------------------------------------------------------------------
// Stage 1: weighted z-buffer scatter. Grid (ceil(N/1024), B); each thread does
// 4 points at grid-stride spacing -> consecutive lanes read consecutive points
// (scalar dword loads, lane stride 12B -> coalescer merges to ~min line txns).
// One u64 fixed-point atomic per valid point (hi=zw*2^20, lo=w*2^22).
// Block (0,0) also inits mm/accum/ticket (consumed only by later kernels).
// ---------------------------------------------------------------------------
__global__ __launch_bounds__(256) void scatter_k(const float* __restrict__ pts,
                          const float* __restrict__ dens,
                          unsigned long long* __restrict__ acc,
                          unsigned* __restrict__ mm, float* __restrict__ accum,
                          unsigned* __restrict__ ticket, int N, int stride) {
    if (blockIdx.x == 0 && blockIdx.y == 0) {
        int tt = threadIdx.x;
        if (tt < 8) mm[tt] = 0xFFFFFFFFu;                 // minP, minG slots
        else if (tt < 16) mm[tt] = 0u;                    // maxP, maxG slots
        else if (tt < 19) accum[tt - 16] = 0.f;           // ssim/mask/l1 sums
        else if (tt == 19) *ticket = 0u;
    }
    int b = blockIdx.y;
    const float* ptsb  = pts  + (size_t)b * N * 3;
    const float* densb = dens + (size_t)b * N;
    unsigned long long* accb = acc + (size_t)b * HW;
    int p0 = blockIdx.x * 256 + threadIdx.x;

    float xs[4], ys[4], zs[4], ds[4];
#pragma unroll
    for (int j = 0; j < 4; ++j) {
        int p = p0 + j * stride;
        bool ok = p < N;
        xs[j] = ok ? ptsb[3 * p]     : 0.f;
        ys[j] = ok ? ptsb[3 * p + 1] : 0.f;
        zs[j] = ok ? ptsb[3 * p + 2] : 0.f;   // z=0 -> fails z>MIN_D -> skipped
        ds[j] = ok ? densb[p]        : 0.f;
    }
#pragma unroll
    for (int j = 0; j < 4; ++j) {
        float z = zs[j];
        if (!(z > MIN_D)) continue;                 // strict z > MIN_DEPTH
        float invz = __builtin_amdgcn_rcpf(z);
        invz = invz * (2.0f - z * invz);            // Newton -> ~1 ulp of 1/z
        float u = (xs[j] * invz + 0.5f) * (float)WW;
        float v = (ys[j] * invz + 0.5f) * (float)HH;
        if (!(u >= 0.f && u < (float)WW && v >= 0.f && v < (float)HH)) continue;
        int ui = (int)u;                            // trunc == floor (u >= 0)
        int vi = (int)v;
        float w = __builtin_amdgcn_rcpf(1.f + __expf(-ds[j]));  // sigmoid
        unsigned hi = (unsigned)__float2int_rn(z * w * ZW_SCALE);
        unsigned lo = (unsigned)__float2int_rn(w * W_SCALE);
        unsigned long long pk = ((unsigned long long)hi << 32) | lo;
        atomicAdd(&accb[(vi << 8) | ui], pk);
    }
}

// ---------------------------------------------------------------------------
// Stage 2: depth = (hi/lo)*4 (where lo>0) -> raw; per-batch min/max of valid
// pred & gt via uint-bit atomics.
// mm layout: [0..3]=minP, [4..7]=minG, [8..11]=maxP, [12..15]=maxG
// ---------------------------------------------------------------------------
__global__ __launch_bounds__(256) void finalize_k(const unsigned long long* __restrict__ acc,
                           const float* __restrict__ gt, float* __restrict__ raw,
                           unsigned* __restrict__ mm) {
    int i = blockIdx.x * 256 + threadIdx.x;
    int b = blockIdx.x >> 8;
    unsigned long long v = acc[i];
    unsigned lo = (unsigned)v;
    unsigned hi = (unsigned)(v >> 32);
    float d = lo ? ((float)hi / (float)lo) * 4.0f : 0.f;   // (hi/2^20)/(lo/2^22)
    raw[i] = d;
    float g = gt[i];
    unsigned dmin = d > 0.f ? __float_as_uint(d) : 0xFFFFFFFFu;
    unsigned dmax = d > 0.f ? __float_as_uint(d) : 0u;
    unsigned gmin = g > 0.f ? __float_as_uint(g) : 0xFFFFFFFFu;
    unsigned gmax = g > 0.f ? __float_as_uint(g) : 0u;
    for (int o = 32; o; o >>= 1) {
        dmin = min(dmin, shdu(dmin, o));
        gmin = min(gmin, shdu(gmin, o));
        dmax = max(dmax, shdu(dmax, o));
        gmax = max(gmax, shdu(gmax, o));
    }
    __shared__ unsigned sm[4][4];
    int wid = threadIdx.x >> 6, lane = threadIdx.x & 63;
    if (lane == 0) { sm[0][wid] = dmin; sm[1][wid] = gmin; sm[2][wid] = dmax; sm[3][wid] = gmax; }
    __syncthreads();
    if (threadIdx.x == 0) {
        unsigned m0 = min(min(sm[0][0], sm[0][1]), min(sm[0][2], sm[0][3]));
        unsigned m1 = min(min(sm[1][0], sm[1][1]), min(sm[1][2], sm[1][3]));
        unsigned m2 = max(max(sm[2][0], sm[2][1]), max(sm[2][2], sm[2][3]));
        unsigned m3 = max(max(sm[3][0], sm[3][1]), max(sm[3][2], sm[3][3]));
        atomicMin(&mm[b], m0);
        atomicMin(&mm[4 + b], m1);
        atomicMax(&mm[8 + b], m2);
        atomicMax(&mm[12 + b], m3);
    }
}

// ---------------------------------------------------------------------------
// Stage 3: fused normalize + separable 11x11 zero-padded box SSIM + masked L1
// + final combine (last block via atomic ticket). Row-band structure:
// block = 256 threads = one column each; 4 output rows per block; 14 guarded
// coalesced row loads into registers; vertical sums in regs; horizontal sums
// via 266-wide zero-padded LDS rows (stride-1, conflict-free).
// accum[0]=ssim_sum, accum[1]=mask_sum, accum[2]=l1_sum
// ---------------------------------------------------------------------------
__global__ __launch_bounds__(256) void ssim_k(const float* __restrict__ raw,
                       const float* __restrict__ gt, const unsigned* __restrict__ mm,
                       float* __restrict__ accum, unsigned* __restrict__ ticket,
                       float* __restrict__ out, int nblocks) {
    __shared__ float hs[5][266];
    __shared__ float sb[3][4];
    int z = blockIdx.y;
    int r0 = blockIdx.x * 4;
    int tx = threadIdx.x;
    const float* P = raw + (size_t)z * HW;
    const float* T = gt + (size_t)z * HW;

    bool hasP = mm[8 + z] != 0u;
    float pmin_m = hasP ? fmaxf(__uint_as_float(mm[z]), MIN_D) : 0.f;
    float pscale = 1.f / ((hasP ? fminf(__uint_as_float(mm[8 + z]), MAX_D) : MAX_D) - pmin_m + 1e-8f);
    bool hasG = mm[12 + z] != 0u;
    float gmin_m = hasG ? fmaxf(__uint_as_float(mm[4 + z]), MIN_D) : 0.f;
    float gscale = 1.f / ((hasG ? fminf(__uint_as_float(mm[12 + z]), MAX_D) : MAX_D) - gmin_m + 1e-8f);

    // 14 rows (r0-5 .. r0+8), normalized; out-of-image rows -> 0 (zero-pad)
    float p[14], t[14];
#pragma unroll
    for (int i = 0; i < 14; ++i) {
        int row = r0 - 5 + i;
        bool ok = (row >= 0) && (row < HH);
        float dv = ok ? P[row * WW + tx] : 0.f;
        float gv = ok ? T[row * WW + tx] : 0.f;
        p[i] = (dv - pmin_m) * pscale * (dv > 0.f ? 1.f : 0.f);
        t[i] = (gv - gmin_m) * gscale * (gv > 0.f ? 1.f : 0.f);
    }
    if (tx < 5) {
#pragma unroll
        for (int q = 0; q < 5; ++q) { hs[q][tx] = 0.f; hs[q][261 + tx] = 0.f; }
    }
    __syncthreads();

    const float inv121 = 1.f / 121.f;
    float svA = 0.f, mA = 0.f, lvA = 0.f;
#pragma unroll
    for (int r = 0; r < 4; ++r) {
        float s1 = 0, s2 = 0, s11 = 0, s22 = 0, s12 = 0;
#pragma unroll
        for (int k = 0; k < 11; ++k) {
            float pp = p[r + k], tt = t[r + k];
            s1 += pp; s2 += tt;
            s11 = fmaf(pp, pp, s11); s22 = fmaf(tt, tt, s22); s12 = fmaf(pp, tt, s12);
        }
        hs[0][5 + tx] = s1; hs[1][5 + tx] = s2; hs[2][5 + tx] = s11;
        hs[3][5 + tx] = s22; hs[4][5 + tx] = s12;
        __syncthreads();
        float h1 = 0, h2 = 0, h11 = 0, h22 = 0, h12 = 0;
#pragma unroll
        for (int k = 0; k < 11; ++k) {
            h1 += hs[0][tx + k]; h2 += hs[1][tx + k]; h11 += hs[2][tx + k];
            h22 += hs[3][tx + k]; h12 += hs[4][tx + k];
        }
        float mu1 = h1 * inv121, mu2 = h2 * inv121;
        float mu1sq = mu1 * mu1, mu2sq = mu2 * mu2, mu12 = mu1 * mu2;
        float sig1 = h11 * inv121 - mu1sq;
        float sig2 = h22 * inv121 - mu2sq;
        float sig12 = h12 * inv121 - mu12;
        float smap = (2.f * mu12 + C1c) * (2.f * sig12 + C2c) /
                     ((mu1sq + mu2sq + C1c) * (sig1 + sig2 + C2c));
        float pc = p[r + 5], tc = t[r + 5];
        float m = (pc > 0.f && tc > 0.f) ? 1.f : 0.f;
        svA += smap * m;
        mA  += m;
        lvA += m * fabsf(pc - tc);
        __syncthreads();
    }

    for (int o = 32; o; o >>= 1) {
        svA += __shfl_down(svA, o, 64);
        mA  += __shfl_down(mA, o, 64);
        lvA += __shfl_down(lvA, o, 64);
    }
    int wid = tx >> 6, lane = tx & 63;
    if (lane == 0) { sb[0][wid] = svA; sb[1][wid] = mA; sb[2][wid] = lvA; }
    __syncthreads();
    if (tx == 0) {
        unsafeAtomicAdd(&accum[0], sb[0][0] + sb[0][1] + sb[0][2] + sb[0][3]);
        unsafeAtomicAdd(&accum[1], sb[1][0] + sb[1][1] + sb[1][2] + sb[1][3]);
        unsafeAtomicAdd(&accum[2], sb[2][0] + sb[2][1] + sb[2][2] + sb[2][3]);
        __threadfence();                       // drain our adds
        unsigned old = atomicAdd(ticket, 1u);
        if (old == (unsigned)(nblocks - 1)) {  // last block: all adds visible
            __threadfence();
            float ss = __hip_atomic_load(&accum[0], __ATOMIC_RELAXED, __HIP_MEMORY_SCOPE_AGENT);
            float ms = __hip_atomic_load(&accum[1], __ATOMIC_RELAXED, __HIP_MEMORY_SCOPE_AGENT);
            float ls = __hip_atomic_load(&accum[2], __ATOMIC_RELAXED, __HIP_MEMORY_SCOPE_AGENT);
            float l1   = ls / (ms + 1e-8f);
            float ssim = 1.f - ss / (ms + 1e-8f);
            float total = fminf(0.8f * l1 + 0.2f * ssim, 1.0f);
            out[0] = (ms < 10.f) ? 0.f : total;
        }
    }
}

extern "C" void kernel_launch(void* const* d_in, const int* in_sizes, int n_in,
                              void* d_out, int out_size, void* d_ws, size_t ws_size,
                              hipStream_t stream) {
    const float* pts = (const float*)d_in[0];
    const float* dens = (const float*)d_in[1];
    const float* gt = (const float*)d_in[2];
    int B = in_sizes[2] / HW;      // 4
    int N = in_sizes[1] / B;       // 2,000,000

    unsigned long long* acc = (unsigned long long*)d_ws;          // [B*HW] u64
    float* raw  = (float*)(acc + (size_t)B * HW);                 // [B*HW] f32
    unsigned* mm = (unsigned*)(raw + (size_t)B * HW);             // 16 u32
    float* accum = (float*)(mm + 16);                             // 3 f32
    unsigned* ticket = (unsigned*)(accum + 3);                    // 1 u32

    hipMemsetAsync(acc, 0, (size_t)B * HW * sizeof(unsigned long long), stream);

    int blocks_x = (N + 1023) / 1024;          // 4 points per thread
    int stride = blocks_x * 256;
    scatter_k<<<dim3(blocks_x, B), 256, 0, stream>>>(pts, dens, acc, mm, accum,
                                                     ticket, N, stride);
    finalize_k<<<B * 256, 256, 0, stream>>>(acc, gt, raw, mm);
    int nblocks = 64 * B;
    ssim_k<<<dim3(64, B), 256, 0, stream>>>(raw, gt, mm, accum, ticket,
                                            (float*)d_out, nblocks);
}

// Round 5
// 106.580 us; speedup vs baseline: 1.6697x; 1.0609x over previous
//
#include <hip/hip_runtime.h>
#include <math.h>

#define HH 256
#define WW 256
static constexpr int HW = HH * WW;
static constexpr float MIN_D = 0.1f;
static constexpr float MAX_D = 10.0f;
static constexpr float C1c = 1e-4f;   // 0.01^2
static constexpr float C2c = 9e-4f;   // 0.03^2
static constexpr float ZW_SCALE = 1048576.f;   // 2^20
static constexpr float W_SCALE  = 4194304.f;   // 2^22

__device__ inline unsigned shdu(unsigned v, int o) {
    return (unsigned)__shfl_down((int)v, o, 64);
}

// ---------------------------------------------------------------------------
// Stage 0: zero the u64 accumulator (16B stores) + init mm/accum/ticket.
// Replaces hipMemsetAsync's fillBufferAligned, which ran at 38 GB/s (55 us).
// ---------------------------------------------------------------------------
__global__ __launch_bounds__(256) void zero_k(ulonglong2* __restrict__ accv,
                          unsigned* __restrict__ mm, float* __restrict__ accum,
                          unsigned* __restrict__ ticket, int n16) {
    int i = blockIdx.x * 256 + threadIdx.x;
    if (i < n16) accv[i] = ulonglong2{0ull, 0ull};
    if (blockIdx.x == 0) {
        int tt = threadIdx.x;
        if (tt < 8) mm[tt] = 0xFFFFFFFFu;                 // minP, minG slots
        else if (tt < 16) mm[tt] = 0u;                    // maxP, maxG slots
        else if (tt < 19) accum[tt - 16] = 0.f;           // ssim/mask/l1 sums
        else if (tt == 19) *ticket = 0u;
    }
}

// ---------------------------------------------------------------------------
// Stage 1: weighted z-buffer scatter. Grid (ceil(N/4/256), B); thread t owns
// 4 CONSECUTIVE points -> 3 dwordx4 (pts) + 1 dwordx4 (dens) = 1 VMEM
// instruction per point (issue-bound optimum); 48B lane stride keeps each
// lane's 16B chunk within one 64B line.
// One u64 fixed-point atomic per valid point (hi=zw*2^20, lo=w*2^22).
// ---------------------------------------------------------------------------
__global__ __launch_bounds__(256) void scatter_k(const float* __restrict__ pts,
                          const float* __restrict__ dens,
                          unsigned long long* __restrict__ acc,
                          int N4) {
    int t = blockIdx.x * 256 + threadIdx.x;
    if (t >= N4) return;
    int b = blockIdx.y;
    const float4* pb4 = (const float4*)(pts + (size_t)b * N4 * 12);
    const float4* db4 = (const float4*)(dens + (size_t)b * N4 * 4);
    unsigned long long* accb = acc + (size_t)b * HW;

    float4 A = pb4[3 * t], Bv = pb4[3 * t + 1], C = pb4[3 * t + 2];
    float4 D = db4[t];
    float xs[4] = {A.x, A.w, Bv.z, C.y};
    float ys[4] = {A.y, Bv.x, Bv.w, C.z};
    float zs[4] = {A.z, Bv.y, C.x, C.w};
    float ds[4] = {D.x, D.y, D.z, D.w};
#pragma unroll
    for (int j = 0; j < 4; ++j) {
        float z = zs[j];
        if (!(z > MIN_D)) continue;                 // strict z > MIN_DEPTH
        float invz = __builtin_amdgcn_rcpf(z);
        invz = invz * (2.0f - z * invz);            // Newton -> ~1 ulp of 1/z
        float u = (xs[j] * invz + 0.5f) * (float)WW;
        float v = (ys[j] * invz + 0.5f) * (float)HH;
        if (!(u >= 0.f && u < (float)WW && v >= 0.f && v < (float)HH)) continue;
        int ui = (int)u;                            // trunc == floor (u >= 0)
        int vi = (int)v;
        float w = __builtin_amdgcn_rcpf(1.f + __expf(-ds[j]));  // sigmoid
        unsigned hi = (unsigned)__float2int_rn(z * w * ZW_SCALE);
        unsigned lo = (unsigned)__float2int_rn(w * W_SCALE);
        unsigned long long pk = ((unsigned long long)hi << 32) | lo;
        atomicAdd(&accb[(vi << 8) | ui], pk);
    }
}

// ---------------------------------------------------------------------------
// Stage 2: depth = (hi/lo)*4 (where lo>0) -> raw; per-batch min/max of valid
// pred & gt via uint-bit atomics.
// mm layout: [0..3]=minP, [4..7]=minG, [8..11]=maxP, [12..15]=maxG
// ---------------------------------------------------------------------------
__global__ __launch_bounds__(256) void finalize_k(const unsigned long long* __restrict__ acc,
                           const float* __restrict__ gt, float* __restrict__ raw,
                           unsigned* __restrict__ mm) {
    int i = blockIdx.x * 256 + threadIdx.x;
    int b = blockIdx.x >> 8;
    unsigned long long v = acc[i];
    unsigned lo = (unsigned)v;
    unsigned hi = (unsigned)(v >> 32);
    float d = lo ? ((float)hi / (float)lo) * 4.0f : 0.f;   // (hi/2^20)/(lo/2^22)
    raw[i] = d;
    float g = gt[i];
    unsigned dmin = d > 0.f ? __float_as_uint(d) : 0xFFFFFFFFu;
    unsigned dmax = d > 0.f ? __float_as_uint(d) : 0u;
    unsigned gmin = g > 0.f ? __float_as_uint(g) : 0xFFFFFFFFu;
    unsigned gmax = g > 0.f ? __float_as_uint(g) : 0u;
    for (int o = 32; o; o >>= 1) {
        dmin = min(dmin, shdu(dmin, o));
        gmin = min(gmin, shdu(gmin, o));
        dmax = max(dmax, shdu(dmax, o));
        gmax = max(gmax, shdu(gmax, o));
    }
    __shared__ unsigned sm[4][4];
    int wid = threadIdx.x >> 6, lane = threadIdx.x & 63;
    if (lane == 0) { sm[0][wid] = dmin; sm[1][wid] = gmin; sm[2][wid] = dmax; sm[3][wid] = gmax; }
    __syncthreads();
    if (threadIdx.x == 0) {
        unsigned m0 = min(min(sm[0][0], sm[0][1]), min(sm[0][2], sm[0][3]));
        unsigned m1 = min(min(sm[1][0], sm[1][1]), min(sm[1][2], sm[1][3]));
        unsigned m2 = max(max(sm[2][0], sm[2][1]), max(sm[2][2], sm[2][3]));
        unsigned m3 = max(max(sm[3][0], sm[3][1]), max(sm[3][2], sm[3][3]));
        atomicMin(&mm[b], m0);
        atomicMin(&mm[4 + b], m1);
        atomicMax(&mm[8 + b], m2);
        atomicMax(&mm[12 + b], m3);
    }
}

// ---------------------------------------------------------------------------
// Stage 3: fused normalize + separable 11x11 zero-padded box SSIM + masked L1
// + final combine (last block via atomic ticket). Row-band structure:
// block = 256 threads = one column each; 4 output rows per block; 14 guarded
// coalesced row loads into registers; vertical sums in regs; horizontal sums
// via 266-wide zero-padded LDS rows (stride-1, conflict-free).
// accum[0]=ssim_sum, accum[1]=mask_sum, accum[2]=l1_sum
// ---------------------------------------------------------------------------
__global__ __launch_bounds__(256) void ssim_k(const float* __restrict__ raw,
                       const float* __restrict__ gt, const unsigned* __restrict__ mm,
                       float* __restrict__ accum, unsigned* __restrict__ ticket,
                       float* __restrict__ out, int nblocks) {
    __shared__ float hs[5][266];
    __shared__ float sb[3][4];
    int z = blockIdx.y;
    int r0 = blockIdx.x * 4;
    int tx = threadIdx.x;
    const float* P = raw + (size_t)z * HW;
    const float* T = gt + (size_t)z * HW;

    bool hasP = mm[8 + z] != 0u;
    float pmin_m = hasP ? fmaxf(__uint_as_float(mm[z]), MIN_D) : 0.f;
    float pscale = 1.f / ((hasP ? fminf(__uint_as_float(mm[8 + z]), MAX_D) : MAX_D) - pmin_m + 1e-8f);
    bool hasG = mm[12 + z] != 0u;
    float gmin_m = hasG ? fmaxf(__uint_as_float(mm[4 + z]), MIN_D) : 0.f;
    float gscale = 1.f / ((hasG ? fminf(__uint_as_float(mm[12 + z]), MAX_D) : MAX_D) - gmin_m + 1e-8f);

    // 14 rows (r0-5 .. r0+8), normalized; out-of-image rows -> 0 (zero-pad)
    float p[14], t[14];
#pragma unroll
    for (int i = 0; i < 14; ++i) {
        int row = r0 - 5 + i;
        bool ok = (row >= 0) && (row < HH);
        float dv = ok ? P[row * WW + tx] : 0.f;
        float gv = ok ? T[row * WW + tx] : 0.f;
        p[i] = (dv - pmin_m) * pscale * (dv > 0.f ? 1.f : 0.f);
        t[i] = (gv - gmin_m) * gscale * (gv > 0.f ? 1.f : 0.f);
    }
    if (tx < 5) {
#pragma unroll
        for (int q = 0; q < 5; ++q) { hs[q][tx] = 0.f; hs[q][261 + tx] = 0.f; }
    }
    __syncthreads();

    const float inv121 = 1.f / 121.f;
    float svA = 0.f, mA = 0.f, lvA = 0.f;
#pragma unroll
    for (int r = 0; r < 4; ++r) {
        float s1 = 0, s2 = 0, s11 = 0, s22 = 0, s12 = 0;
#pragma unroll
        for (int k = 0; k < 11; ++k) {
            float pp = p[r + k], tt = t[r + k];
            s1 += pp; s2 += tt;
            s11 = fmaf(pp, pp, s11); s22 = fmaf(tt, tt, s22); s12 = fmaf(pp, tt, s12);
        }
        hs[0][5 + tx] = s1; hs[1][5 + tx] = s2; hs[2][5 + tx] = s11;
        hs[3][5 + tx] = s22; hs[4][5 + tx] = s12;
        __syncthreads();
        float h1 = 0, h2 = 0, h11 = 0, h22 = 0, h12 = 0;
#pragma unroll
        for (int k = 0; k < 11; ++k) {
            h1 += hs[0][tx + k]; h2 += hs[1][tx + k]; h11 += hs[2][tx + k];
            h22 += hs[3][tx + k]; h12 += hs[4][tx + k];
        }
        float mu1 = h1 * inv121, mu2 = h2 * inv121;
        float mu1sq = mu1 * mu1, mu2sq = mu2 * mu2, mu12 = mu1 * mu2;
        float sig1 = h11 * inv121 - mu1sq;
        float sig2 = h22 * inv121 - mu2sq;
        float sig12 = h12 * inv121 - mu12;
        float smap = (2.f * mu12 + C1c) * (2.f * sig12 + C2c) /
                     ((mu1sq + mu2sq + C1c) * (sig1 + sig2 + C2c));
        float pc = p[r + 5], tc = t[r + 5];
        float m = (pc > 0.f && tc > 0.f) ? 1.f : 0.f;
        svA += smap * m;
        mA  += m;
        lvA += m * fabsf(pc - tc);
        __syncthreads();
    }

    for (int o = 32; o; o >>= 1) {
        svA += __shfl_down(svA, o, 64);
        mA  += __shfl_down(mA, o, 64);
        lvA += __shfl_down(lvA, o, 64);
    }
    int wid = tx >> 6, lane = tx & 63;
    if (lane == 0) { sb[0][wid] = svA; sb[1][wid] = mA; sb[2][wid] = lvA; }
    __syncthreads();
    if (tx == 0) {
        unsafeAtomicAdd(&accum[0], sb[0][0] + sb[0][1] + sb[0][2] + sb[0][3]);
        unsafeAtomicAdd(&accum[1], sb[1][0] + sb[1][1] + sb[1][2] + sb[1][3]);
        unsafeAtomicAdd(&accum[2], sb[2][0] + sb[2][1] + sb[2][2] + sb[2][3]);
        __threadfence();                       // drain our adds
        unsigned old = atomicAdd(ticket, 1u);
        if (old == (unsigned)(nblocks - 1)) {  // last block: all adds visible
            __threadfence();
            float ss = __hip_atomic_load(&accum[0], __ATOMIC_RELAXED, __HIP_MEMORY_SCOPE_AGENT);
            float ms = __hip_atomic_load(&accum[1], __ATOMIC_RELAXED, __HIP_MEMORY_SCOPE_AGENT);
            float ls = __hip_atomic_load(&accum[2], __ATOMIC_RELAXED, __HIP_MEMORY_SCOPE_AGENT);
            float l1   = ls / (ms + 1e-8f);
            float ssim = 1.f - ss / (ms + 1e-8f);
            float total = fminf(0.8f * l1 + 0.2f * ssim, 1.0f);
            out[0] = (ms < 10.f) ? 0.f : total;
        }
    }
}

extern "C" void kernel_launch(void* const* d_in, const int* in_sizes, int n_in,
                              void* d_out, int out_size, void* d_ws, size_t ws_size,
                              hipStream_t stream) {
    const float* pts = (const float*)d_in[0];
    const float* dens = (const float*)d_in[1];
    const float* gt = (const float*)d_in[2];
    int B = in_sizes[2] / HW;      // 4
    int N = in_sizes[1] / B;       // 2,000,000

    unsigned long long* acc = (unsigned long long*)d_ws;          // [B*HW] u64
    float* raw  = (float*)(acc + (size_t)B * HW);                 // [B*HW] f32
    unsigned* mm = (unsigned*)(raw + (size_t)B * HW);             // 16 u32
    float* accum = (float*)(mm + 16);                             // 3 f32
    unsigned* ticket = (unsigned*)(accum + 3);                    // 1 u32

    int n16 = B * HW / 2;                      // ulonglong2 count
    zero_k<<<(n16 + 255) / 256, 256, 0, stream>>>((ulonglong2*)acc, mm, accum,
                                                  ticket, n16);

    int N4 = N / 4;                            // 4 consecutive points / thread
    scatter_k<<<dim3((N4 + 255) / 256, B), 256, 0, stream>>>(pts, dens, acc, N4);
    finalize_k<<<B * 256, 256, 0, stream>>>(acc, gt, raw, mm);
    int nblocks = 64 * B;
    ssim_k<<<dim3(64, B), 256, 0, stream>>>(raw, gt, mm, accum, ticket,
                                            (float*)d_out, nblocks);
}